// Round 2
// baseline (1547.470 us; speedup 1.0000x reference)
//
#include <hip/hip_runtime.h>
#include <hip/hip_bf16.h>

// NodeModel: edge MLP ([x[col]||edge_attr] -> 64 relu -> 64 relu) -> scatter_mean
// over row -> node MLP ([x||agg||u[batch]] -> 64 relu -> 32).
// N=50000, E=1.6M, D_H=64.
//
// R2: edge MLP via bf16 MFMA (16x16x32), f32 accumulate. Transposed compute:
//   D = W^T (A-operand, VGPR-resident) x In^T (B-operand from swizzled LDS).
// C/D layout (m89-verified): col=lane&15 (edge), row=4*(lane>>4)+reg (neuron).
// A layout: row=lane&15, k=8*(lane>>4)+j.  B layout: col=lane&15, k=8*(lane>>4)+j.
// Each wave owns 16 edges/iter; LDS regions are wave-private -> NO barriers.
// Scatter via f32 HW atomics; counts via separate histogram kernel; node MLP f32.

typedef __attribute__((ext_vector_type(8))) short bf16x8;
typedef __attribute__((ext_vector_type(4))) float f32x4;

__device__ __forceinline__ unsigned short f2bf(float f) {
    union { float f; unsigned u; } v; v.f = f;
    return (unsigned short)((v.u + 0x7FFFu + ((v.u >> 16) & 1u)) >> 16);
}

__global__ __launch_bounds__(256, 3) void edge_mlp_mfma(
    const float* __restrict__ x,      // [N,32]
    const int*   __restrict__ erow,   // [E]
    const int*   __restrict__ ecol,   // [E]
    const float* __restrict__ eattr,  // [E,32]
    const float* __restrict__ W1a,    // [64,64] (in,out)
    const float* __restrict__ b1a,    // [64]
    const float* __restrict__ W1b,    // [64,64]
    const float* __restrict__ b1b,    // [64]
    float* __restrict__ summed,       // [N,64]
    int E)
{
    // [64 local edges][64 bf16], 16B-chunk XOR-swizzled by (edge&7); wave-private rows
    __shared__ __align__(16) unsigned short In[64 * 64];
    __shared__ __align__(16) unsigned short H2[64 * 64];

    const int tid  = threadIdx.x;
    const int lane = tid & 63;
    const int wv   = tid >> 6;
    const int g    = lane >> 4;   // lane group 0..3
    const int el   = lane & 15;   // edge-in-tile (mfma col)

    // ---- persistent weight fragments: A-operand = W^T  (out = M, in = K) ----
    bf16x8 wa[4][2], wb[4][2];
    f32x4  bias1[4], bias2[4];
#pragma unroll
    for (int mt = 0; mt < 4; ++mt) {
        const int o = mt * 16 + el;          // output neuron = A row = lane&15
#pragma unroll
        for (int ks = 0; ks < 2; ++ks) {
            bf16x8 ta, tb;
#pragma unroll
            for (int j = 0; j < 8; ++j) {
                const int k = ks * 32 + 8 * g + j;   // K index = 8*(lane>>4)+j
                ta[j] = (short)f2bf(W1a[k * 64 + o]);
                tb[j] = (short)f2bf(W1b[k * 64 + o]);
            }
            wa[mt][ks] = ta;
            wb[mt][ks] = tb;
        }
#pragma unroll
        for (int r = 0; r < 4; ++r) {        // D row = 4*(lane>>4)+reg
            bias1[mt][r] = b1a[mt * 16 + 4 * g + r];
            bias2[mt][r] = b1b[mt * 16 + 4 * g + r];
        }
    }

    unsigned short* const inrow = In + (wv * 16) * 64;
    unsigned short* const h2row = H2 + (wv * 16) * 64;

    const int ntile = (E + 15) >> 4;              // 16-edge tiles
    const int wid   = blockIdx.x * 4 + wv;
    const int nw    = gridDim.x * 4;

    for (int t = wid; t < ntile; t += nw) {
        const int ebase = t << 4;

        // ---- stage 16 edges: 4 lanes/edge, 16 f32 each -> bf16 -> swizzled LDS ----
        {
            const int le = lane >> 2;             // local edge 0..15
            const int p  = lane & 3;              // quarter of the 64-wide input row
            const int e  = ebase + le;
            float4 v[4];
            if (e < E) {
                const float* src;
                if (p < 2) {
                    const int c = ecol[e];
                    src = x + (size_t)c * 32 + p * 16;
                } else {
                    src = eattr + (size_t)e * 32 + (p - 2) * 16;
                }
#pragma unroll
                for (int q = 0; q < 4; ++q) v[q] = ((const float4*)src)[q];
            } else {
#pragma unroll
                for (int q = 0; q < 4; ++q) v[q] = float4{0.f, 0.f, 0.f, 0.f};
            }
            bf16x8 c0, c1;
#pragma unroll
            for (int q = 0; q < 2; ++q) {
                c0[4*q+0] = (short)f2bf(v[q].x); c0[4*q+1] = (short)f2bf(v[q].y);
                c0[4*q+2] = (short)f2bf(v[q].z); c0[4*q+3] = (short)f2bf(v[q].w);
                c1[4*q+0] = (short)f2bf(v[q+2].x); c1[4*q+1] = (short)f2bf(v[q+2].y);
                c1[4*q+2] = (short)f2bf(v[q+2].z); c1[4*q+3] = (short)f2bf(v[q+2].w);
            }
            const int sw = le & 7;
            unsigned short* row = inrow + le * 64;
            *(bf16x8*)(row + (((2 * p)     ^ sw) * 8)) = c0;
            *(bf16x8*)(row + (((2 * p + 1) ^ sw) * 8)) = c1;
        }
        // wave-private LDS: compiler-inserted lgkmcnt orders write->read; no barrier

        const int sw = el & 7;

        // ---- layer 1: D1 = W1a^T x In^T  (M=64 out, N=16 edges, K=64) ----
        const unsigned short* brow = inrow + el * 64;
        const bf16x8 bf0 = *(const bf16x8*)(brow + (((0 + g) ^ sw) * 8));  // k=8g.., ks=0
        const bf16x8 bf1 = *(const bf16x8*)(brow + (((4 + g) ^ sw) * 8));  // ks=1
        f32x4 a0 = bias1[0], a1 = bias1[1], a2 = bias1[2], a3 = bias1[3];
        a0 = __builtin_amdgcn_mfma_f32_16x16x32_bf16(wa[0][0], bf0, a0, 0, 0, 0);
        a1 = __builtin_amdgcn_mfma_f32_16x16x32_bf16(wa[1][0], bf0, a1, 0, 0, 0);
        a2 = __builtin_amdgcn_mfma_f32_16x16x32_bf16(wa[2][0], bf0, a2, 0, 0, 0);
        a3 = __builtin_amdgcn_mfma_f32_16x16x32_bf16(wa[3][0], bf0, a3, 0, 0, 0);
        a0 = __builtin_amdgcn_mfma_f32_16x16x32_bf16(wa[0][1], bf1, a0, 0, 0, 0);
        a1 = __builtin_amdgcn_mfma_f32_16x16x32_bf16(wa[1][1], bf1, a1, 0, 0, 0);
        a2 = __builtin_amdgcn_mfma_f32_16x16x32_bf16(wa[2][1], bf1, a2, 0, 0, 0);
        a3 = __builtin_amdgcn_mfma_f32_16x16x32_bf16(wa[3][1], bf1, a3, 0, 0, 0);

        // ---- relu -> bf16 -> H2[edge][hidden] (wave-private, swizzled) ----
        unsigned short* hrow = h2row + el * 64;
        {
            f32x4 accs[4] = {a0, a1, a2, a3};
#pragma unroll
            for (int mt = 0; mt < 4; ++mt) {
                unsigned short pk[4];
#pragma unroll
                for (int r = 0; r < 4; ++r) pk[r] = f2bf(fmaxf(accs[mt][r], 0.f));
                const int hid   = mt * 16 + 4 * g;       // 4 consecutive hidden
                const int chunk = hid >> 3;
                const int off   = hid & 7;               // 0 or 4
                unsigned short* wp = hrow + ((chunk ^ sw) * 8 + off);
                *(uint2*)wp = *(uint2*)pk;               // 8B store
            }
        }

        // ---- layer 2: D2 = W1b^T x relu(H1)^T ----
        const bf16x8 hb0 = *(const bf16x8*)(hrow + (((0 + g) ^ sw) * 8));
        const bf16x8 hb1 = *(const bf16x8*)(hrow + (((4 + g) ^ sw) * 8));
        f32x4 d0 = bias2[0], d1 = bias2[1], d2 = bias2[2], d3 = bias2[3];
        d0 = __builtin_amdgcn_mfma_f32_16x16x32_bf16(wb[0][0], hb0, d0, 0, 0, 0);
        d1 = __builtin_amdgcn_mfma_f32_16x16x32_bf16(wb[1][0], hb0, d1, 0, 0, 0);
        d2 = __builtin_amdgcn_mfma_f32_16x16x32_bf16(wb[2][0], hb0, d2, 0, 0, 0);
        d3 = __builtin_amdgcn_mfma_f32_16x16x32_bf16(wb[3][0], hb0, d3, 0, 0, 0);
        d0 = __builtin_amdgcn_mfma_f32_16x16x32_bf16(wb[0][1], hb1, d0, 0, 0, 0);
        d1 = __builtin_amdgcn_mfma_f32_16x16x32_bf16(wb[1][1], hb1, d1, 0, 0, 0);
        d2 = __builtin_amdgcn_mfma_f32_16x16x32_bf16(wb[2][1], hb1, d2, 0, 0, 0);
        d3 = __builtin_amdgcn_mfma_f32_16x16x32_bf16(wb[3][1], hb1, d3, 0, 0, 0);

        // ---- relu + atomic scatter: lane's edge = ebase+el, outs mt*16+4g+r ----
        const int e = ebase + el;
        if (e < E) {
            const int rr = erow[e];
            float* dst = summed + (size_t)rr * 64 + 4 * g;
            f32x4 ds[4] = {d0, d1, d2, d3};
#pragma unroll
            for (int mt = 0; mt < 4; ++mt)
#pragma unroll
                for (int r = 0; r < 4; ++r)
                    unsafeAtomicAdd(&dst[mt * 16 + r], fmaxf(ds[mt][r], 0.f));
        }
    }
}

__global__ __launch_bounds__(256) void count_rows(
    const int* __restrict__ erow, float* __restrict__ counts, int E)
{
    int i = blockIdx.x * blockDim.x + threadIdx.x;
    const int stride = gridDim.x * blockDim.x;
    for (; i < E; i += stride) unsafeAtomicAdd(&counts[erow[i]], 1.0f);
}

__global__ __launch_bounds__(256) void node_mlp(
    const float* __restrict__ x,      // [N,32]
    const float* __restrict__ summed, // [N,64]
    const float* __restrict__ counts, // [N]
    const float* __restrict__ u,      // [G,16]
    const int*   __restrict__ batch,  // [N]
    const float* __restrict__ W2a,    // [112,64]
    const float* __restrict__ b2a,    // [64]
    const float* __restrict__ W2b,    // [64,32]
    const float* __restrict__ b2b,    // [32]
    float* __restrict__ out,          // [N,32]
    int N_)
{
    const int lane = threadIdx.x & 63;
    const int wid  = blockIdx.x * (blockDim.x >> 6) + (threadIdx.x >> 6);
    const int nw   = gridDim.x * (blockDim.x >> 6);

    float wa[112];
#pragma unroll
    for (int k = 0; k < 112; ++k) wa[k] = W2a[k * 64 + lane];
    const int oc = lane & 31;
    float wb[64];
#pragma unroll
    for (int k = 0; k < 64; ++k) wb[k] = W2b[k * 32 + oc];
    const float ba    = b2a[lane];
    const float bbias = b2b[oc];

    for (int n = wid; n < N_; n += nw) {
        const int g = __builtin_amdgcn_readfirstlane(batch[n]);
        const float* __restrict__ xp = x + (size_t)n * 32;
        const float* __restrict__ sp = summed + (size_t)n * 64;
        const float* __restrict__ up = u + (size_t)g * 16;
        const float inv = 1.0f / fmaxf(counts[n], 1.0f);

        // 4 independent partial chains to break FMA latency serialization
        float p0 = 0.f, p1 = 0.f, p2 = 0.f, p3 = 0.f;
#pragma unroll
        for (int k = 0; k < 32; k += 4) {
            p0 = fmaf(xp[k],     wa[k],     p0);
            p1 = fmaf(xp[k + 1], wa[k + 1], p1);
            p2 = fmaf(xp[k + 2], wa[k + 2], p2);
            p3 = fmaf(xp[k + 3], wa[k + 3], p3);
        }
#pragma unroll
        for (int k = 0; k < 64; k += 4) {
            p0 = fmaf(sp[k]     * inv, wa[32 + k],     p0);
            p1 = fmaf(sp[k + 1] * inv, wa[33 + k],     p1);
            p2 = fmaf(sp[k + 2] * inv, wa[34 + k],     p2);
            p3 = fmaf(sp[k + 3] * inv, wa[35 + k],     p3);
        }
#pragma unroll
        for (int k = 0; k < 16; k += 4) {
            p0 = fmaf(up[k],     wa[96 + k], p0);
            p1 = fmaf(up[k + 1], wa[97 + k], p1);
            p2 = fmaf(up[k + 2], wa[98 + k], p2);
            p3 = fmaf(up[k + 3], wa[99 + k], p3);
        }
        const float z = fmaxf(ba + ((p0 + p1) + (p2 + p3)), 0.0f);

        float q0 = bbias, q1 = 0.f, q2 = 0.f, q3 = 0.f;
#pragma unroll
        for (int k = 0; k < 64; k += 4) {
            q0 = fmaf(__shfl(z, k),     wb[k],     q0);
            q1 = fmaf(__shfl(z, k + 1), wb[k + 1], q1);
            q2 = fmaf(__shfl(z, k + 2), wb[k + 2], q2);
            q3 = fmaf(__shfl(z, k + 3), wb[k + 3], q3);
        }
        if (lane < 32) out[(size_t)n * 32 + lane] = (q0 + q1) + (q2 + q3);
    }
}

extern "C" void kernel_launch(void* const* d_in, const int* in_sizes, int n_in,
                              void* d_out, int out_size, void* d_ws, size_t ws_size,
                              hipStream_t stream) {
    const float* x     = (const float*)d_in[0];
    const int*   eidx  = (const int*)d_in[1];   // [2,E] int32
    const float* eattr = (const float*)d_in[2];
    const float* u     = (const float*)d_in[3];
    const int*   batch = (const int*)d_in[4];
    const float* W1a   = (const float*)d_in[5];
    const float* b1a   = (const float*)d_in[6];
    const float* W1b   = (const float*)d_in[7];
    const float* b1b   = (const float*)d_in[8];
    const float* W2a   = (const float*)d_in[9];
    const float* b2a   = (const float*)d_in[10];
    const float* W2b   = (const float*)d_in[11];
    const float* b2b   = (const float*)d_in[12];
    float* out = (float*)d_out;

    const int N = in_sizes[0] / 32;
    const int E = in_sizes[1] / 2;
    const int* erow = eidx;
    const int* ecol = eidx + E;

    float* summed = (float*)d_ws;                 // [N,64]
    float* counts = summed + (size_t)N * 64;      // [N]
    hipMemsetAsync(d_ws, 0, ((size_t)N * 64 + N) * sizeof(float), stream);

    count_rows<<<2048, 256, 0, stream>>>(erow, counts, E);
    edge_mlp_mfma<<<4096, 256, 0, stream>>>(x, erow, ecol, eattr,
                                            W1a, b1a, W1b, b1b, summed, E);
    node_mlp<<<1024, 256, 0, stream>>>(x, summed, counts, u, batch,
                                       W2a, b2a, W2b, b2b, out, N);
}

// Round 3
// 511.469 us; speedup vs baseline: 3.0255x; 3.0255x over previous
//
#include <hip/hip_runtime.h>
#include <hip/hip_bf16.h>

// NodeModel: edge MLP ([x[col]||edge_attr] -> 64 relu -> 64 relu) -> scatter_mean
// over row -> node MLP ([x||agg||u[batch]] -> 64 relu -> 32).
// N=50000, E=1.6M, D_H=64.
//
// R3: layer-2 MFMA operand order swapped (A=H1, B=W1b) so D2 comes out
// EDGE-major: lane holds edge 4g+r, neuron nt*16+el. The scatter's atomic
// instructions are then fully line-coalesced: lanes 0-15 cover 16 contiguous
// dwords (one 64B line) of one summed row -> 64 full-line visits / 4KB tile
// (was: 256 quarter-line visits -> 4x write amplification, 1.6GB EA traffic).

typedef __attribute__((ext_vector_type(8))) short bf16x8;
typedef __attribute__((ext_vector_type(4))) float f32x4;

__device__ __forceinline__ unsigned short f2bf(float f) {
    union { float f; unsigned u; } v; v.f = f;
    return (unsigned short)((v.u + 0x7FFFu + ((v.u >> 16) & 1u)) >> 16);
}

__global__ __launch_bounds__(256, 3) void edge_mlp_mfma(
    const float* __restrict__ x,      // [N,32]
    const int*   __restrict__ erow,   // [E]
    const int*   __restrict__ ecol,   // [E]
    const float* __restrict__ eattr,  // [E,32]
    const float* __restrict__ W1a,    // [64,64] (in,out)
    const float* __restrict__ b1a,    // [64]
    const float* __restrict__ W1b,    // [64,64]
    const float* __restrict__ b1b,    // [64]
    float* __restrict__ summed,       // [N,64]
    int E)
{
    // [64 local edges][64 bf16], 16B-chunk XOR-swizzled by (edge&7); wave-private rows
    __shared__ __align__(16) unsigned short In[64 * 64];
    __shared__ __align__(16) unsigned short H2[64 * 64];

    const int tid  = threadIdx.x;
    const int lane = tid & 63;
    const int wv   = tid >> 6;
    const int g    = lane >> 4;   // lane group 0..3
    const int el   = lane & 15;   // mfma row/col index

    // ---- persistent weight fragments ----
    // wa[mt]: A-operand of layer 1 = W1a^T  (row = out neuron mt*16+el, k = in)
    // wb[nt]: B-operand of layer 2 = W1b    (col = out neuron nt*16+el, k = hidden)
    //         (A and B lane mappings are identical: idx=lane&15, k=8*(lane>>4)+j)
    bf16x8 wa[4][2], wb[4][2];
    f32x4  bias1[4];
    float  bias2s[4];
#pragma unroll
    for (int mt = 0; mt < 4; ++mt) {
        const int o = mt * 16 + el;
#pragma unroll
        for (int ks = 0; ks < 2; ++ks) {
            bf16x8 ta, tb;
#pragma unroll
            for (int j = 0; j < 8; ++j) {
                const int k = ks * 32 + 8 * g + j;
                ta[j] = (short)f2bf(W1a[k * 64 + o]);
                tb[j] = (short)f2bf(W1b[k * 64 + o]);
            }
            wa[mt][ks] = ta;
            wb[mt][ks] = tb;
        }
#pragma unroll
        for (int r = 0; r < 4; ++r) bias1[mt][r] = b1a[mt * 16 + 4 * g + r];
        bias2s[mt] = b1b[o];
    }

    unsigned short* const inrow = In + (wv * 16) * 64;
    unsigned short* const h2row = H2 + (wv * 16) * 64;

    const int ntile = (E + 15) >> 4;              // 16-edge tiles
    const int wid   = blockIdx.x * 4 + wv;
    const int nw    = gridDim.x * 4;

    for (int t = wid; t < ntile; t += nw) {
        const int ebase = t << 4;

        // ---- stage 16 edges: 4 lanes/edge, 16 f32 each -> bf16 -> swizzled LDS ----
        {
            const int le = lane >> 2;             // local edge 0..15
            const int p  = lane & 3;              // quarter of the 64-wide input row
            const int e  = ebase + le;
            float4 v[4];
            if (e < E) {
                const float* src;
                if (p < 2) {
                    const int c = ecol[e];
                    src = x + (size_t)c * 32 + p * 16;
                } else {
                    src = eattr + (size_t)e * 32 + (p - 2) * 16;
                }
#pragma unroll
                for (int q = 0; q < 4; ++q) v[q] = ((const float4*)src)[q];
            } else {
#pragma unroll
                for (int q = 0; q < 4; ++q) v[q] = float4{0.f, 0.f, 0.f, 0.f};
            }
            bf16x8 c0, c1;
#pragma unroll
            for (int q = 0; q < 2; ++q) {
                c0[4*q+0] = (short)f2bf(v[q].x); c0[4*q+1] = (short)f2bf(v[q].y);
                c0[4*q+2] = (short)f2bf(v[q].z); c0[4*q+3] = (short)f2bf(v[q].w);
                c1[4*q+0] = (short)f2bf(v[q+2].x); c1[4*q+1] = (short)f2bf(v[q+2].y);
                c1[4*q+2] = (short)f2bf(v[q+2].z); c1[4*q+3] = (short)f2bf(v[q+2].w);
            }
            const int sw = le & 7;
            unsigned short* row = inrow + le * 64;
            *(bf16x8*)(row + (((2 * p)     ^ sw) * 8)) = c0;
            *(bf16x8*)(row + (((2 * p + 1) ^ sw) * 8)) = c1;
        }
        // wave-private LDS: compiler-inserted lgkmcnt orders write->read; no barrier

        const int sw = el & 7;

        // ---- layer 1: D1 = W1a^T (A) x In^T (B)  -> out-major (neuron rows) ----
        const unsigned short* brow = inrow + el * 64;
        const bf16x8 bf0 = *(const bf16x8*)(brow + (((0 + g) ^ sw) * 8));
        const bf16x8 bf1 = *(const bf16x8*)(brow + (((4 + g) ^ sw) * 8));
        f32x4 a0 = bias1[0], a1 = bias1[1], a2 = bias1[2], a3 = bias1[3];
        a0 = __builtin_amdgcn_mfma_f32_16x16x32_bf16(wa[0][0], bf0, a0, 0, 0, 0);
        a1 = __builtin_amdgcn_mfma_f32_16x16x32_bf16(wa[1][0], bf0, a1, 0, 0, 0);
        a2 = __builtin_amdgcn_mfma_f32_16x16x32_bf16(wa[2][0], bf0, a2, 0, 0, 0);
        a3 = __builtin_amdgcn_mfma_f32_16x16x32_bf16(wa[3][0], bf0, a3, 0, 0, 0);
        a0 = __builtin_amdgcn_mfma_f32_16x16x32_bf16(wa[0][1], bf1, a0, 0, 0, 0);
        a1 = __builtin_amdgcn_mfma_f32_16x16x32_bf16(wa[1][1], bf1, a1, 0, 0, 0);
        a2 = __builtin_amdgcn_mfma_f32_16x16x32_bf16(wa[2][1], bf1, a2, 0, 0, 0);
        a3 = __builtin_amdgcn_mfma_f32_16x16x32_bf16(wa[3][1], bf1, a3, 0, 0, 0);

        // ---- relu -> bf16 -> H2[edge][hidden] (wave-private, swizzled) ----
        unsigned short* hrow = h2row + el * 64;
        {
            f32x4 accs[4] = {a0, a1, a2, a3};
#pragma unroll
            for (int mt = 0; mt < 4; ++mt) {
                unsigned short pk[4];
#pragma unroll
                for (int r = 0; r < 4; ++r) pk[r] = f2bf(fmaxf(accs[mt][r], 0.f));
                const int hid   = mt * 16 + 4 * g;
                const int chunk = hid >> 3;
                const int off   = hid & 7;
                unsigned short* wp = hrow + ((chunk ^ sw) * 8 + off);
                *(uint2*)wp = *(uint2*)pk;
            }
        }

        // ---- layer 2, operand-swapped: D2 = H1 (A) x W1b (B) -> EDGE-major ----
        // lane holds D2[edge 4g+r][out nt*16+el]
        const bf16x8 hb0 = *(const bf16x8*)(hrow + (((0 + g) ^ sw) * 8));
        const bf16x8 hb1 = *(const bf16x8*)(hrow + (((4 + g) ^ sw) * 8));
        f32x4 d0 = {bias2s[0], bias2s[0], bias2s[0], bias2s[0]};
        f32x4 d1 = {bias2s[1], bias2s[1], bias2s[1], bias2s[1]};
        f32x4 d2 = {bias2s[2], bias2s[2], bias2s[2], bias2s[2]};
        f32x4 d3 = {bias2s[3], bias2s[3], bias2s[3], bias2s[3]};
        d0 = __builtin_amdgcn_mfma_f32_16x16x32_bf16(hb0, wb[0][0], d0, 0, 0, 0);
        d1 = __builtin_amdgcn_mfma_f32_16x16x32_bf16(hb0, wb[1][0], d1, 0, 0, 0);
        d2 = __builtin_amdgcn_mfma_f32_16x16x32_bf16(hb0, wb[2][0], d2, 0, 0, 0);
        d3 = __builtin_amdgcn_mfma_f32_16x16x32_bf16(hb0, wb[3][0], d3, 0, 0, 0);
        d0 = __builtin_amdgcn_mfma_f32_16x16x32_bf16(hb1, wb[0][1], d0, 0, 0, 0);
        d1 = __builtin_amdgcn_mfma_f32_16x16x32_bf16(hb1, wb[1][1], d1, 0, 0, 0);
        d2 = __builtin_amdgcn_mfma_f32_16x16x32_bf16(hb1, wb[2][1], d2, 0, 0, 0);
        d3 = __builtin_amdgcn_mfma_f32_16x16x32_bf16(hb1, wb[3][1], d3, 0, 0, 0);

        // ---- relu + coalesced atomic scatter ----
        // instruction (r,nt): lanes el=0..15 cover 16 contiguous dwords of
        // summed[row(edge 4g+r)] + nt*16 -> full 64B lines, 4 rows/instr.
        f32x4 dd[4] = {d0, d1, d2, d3};
        if (ebase + 16 <= E) {
            const int4 r4 = *(const int4*)(erow + ebase + 4 * g);
            const int rows[4] = {r4.x, r4.y, r4.z, r4.w};
#pragma unroll
            for (int r = 0; r < 4; ++r) {
                float* dst = summed + (size_t)rows[r] * 64 + el;
#pragma unroll
                for (int nt = 0; nt < 4; ++nt)
                    unsafeAtomicAdd(&dst[nt * 16], fmaxf(dd[nt][r], 0.f));
            }
        } else {
#pragma unroll
            for (int r = 0; r < 4; ++r) {
                const int e = ebase + 4 * g + r;
                if (e < E) {
                    float* dst = summed + (size_t)erow[e] * 64 + el;
#pragma unroll
                    for (int nt = 0; nt < 4; ++nt)
                        unsafeAtomicAdd(&dst[nt * 16], fmaxf(dd[nt][r], 0.f));
                }
            }
        }
    }
}

__global__ __launch_bounds__(256) void count_rows(
    const int* __restrict__ erow, float* __restrict__ counts, int E)
{
    int i = blockIdx.x * blockDim.x + threadIdx.x;
    const int stride = gridDim.x * blockDim.x;
    for (; i < E; i += stride) unsafeAtomicAdd(&counts[erow[i]], 1.0f);
}

__global__ __launch_bounds__(256) void node_mlp(
    const float* __restrict__ x,      // [N,32]
    const float* __restrict__ summed, // [N,64]
    const float* __restrict__ counts, // [N]
    const float* __restrict__ u,      // [G,16]
    const int*   __restrict__ batch,  // [N]
    const float* __restrict__ W2a,    // [112,64]
    const float* __restrict__ b2a,    // [64]
    const float* __restrict__ W2b,    // [64,32]
    const float* __restrict__ b2b,    // [32]
    float* __restrict__ out,          // [N,32]
    int N_)
{
    const int lane = threadIdx.x & 63;
    const int wid  = blockIdx.x * (blockDim.x >> 6) + (threadIdx.x >> 6);
    const int nw   = gridDim.x * (blockDim.x >> 6);

    float wa[112];
#pragma unroll
    for (int k = 0; k < 112; ++k) wa[k] = W2a[k * 64 + lane];
    const int oc = lane & 31;
    float wb[64];
#pragma unroll
    for (int k = 0; k < 64; ++k) wb[k] = W2b[k * 32 + oc];
    const float ba    = b2a[lane];
    const float bbias = b2b[oc];

    for (int n = wid; n < N_; n += nw) {
        const int g = __builtin_amdgcn_readfirstlane(batch[n]);
        const float* __restrict__ xp = x + (size_t)n * 32;
        const float* __restrict__ sp = summed + (size_t)n * 64;
        const float* __restrict__ up = u + (size_t)g * 16;
        const float inv = 1.0f / fmaxf(counts[n], 1.0f);

        float p0 = 0.f, p1 = 0.f, p2 = 0.f, p3 = 0.f;
#pragma unroll
        for (int k = 0; k < 32; k += 4) {
            p0 = fmaf(xp[k],     wa[k],     p0);
            p1 = fmaf(xp[k + 1], wa[k + 1], p1);
            p2 = fmaf(xp[k + 2], wa[k + 2], p2);
            p3 = fmaf(xp[k + 3], wa[k + 3], p3);
        }
#pragma unroll
        for (int k = 0; k < 64; k += 4) {
            p0 = fmaf(sp[k]     * inv, wa[32 + k], p0);
            p1 = fmaf(sp[k + 1] * inv, wa[33 + k], p1);
            p2 = fmaf(sp[k + 2] * inv, wa[34 + k], p2);
            p3 = fmaf(sp[k + 3] * inv, wa[35 + k], p3);
        }
#pragma unroll
        for (int k = 0; k < 16; k += 4) {
            p0 = fmaf(up[k],     wa[96 + k], p0);
            p1 = fmaf(up[k + 1], wa[97 + k], p1);
            p2 = fmaf(up[k + 2], wa[98 + k], p2);
            p3 = fmaf(up[k + 3], wa[99 + k], p3);
        }
        const float z = fmaxf(ba + ((p0 + p1) + (p2 + p3)), 0.0f);

        float q0 = bbias, q1 = 0.f, q2 = 0.f, q3 = 0.f;
#pragma unroll
        for (int k = 0; k < 64; k += 4) {
            q0 = fmaf(__shfl(z, k),     wb[k],     q0);
            q1 = fmaf(__shfl(z, k + 1), wb[k + 1], q1);
            q2 = fmaf(__shfl(z, k + 2), wb[k + 2], q2);
            q3 = fmaf(__shfl(z, k + 3), wb[k + 3], q3);
        }
        if (lane < 32) out[(size_t)n * 32 + lane] = (q0 + q1) + (q2 + q3);
    }
}

extern "C" void kernel_launch(void* const* d_in, const int* in_sizes, int n_in,
                              void* d_out, int out_size, void* d_ws, size_t ws_size,
                              hipStream_t stream) {
    const float* x     = (const float*)d_in[0];
    const int*   eidx  = (const int*)d_in[1];   // [2,E] int32
    const float* eattr = (const float*)d_in[2];
    const float* u     = (const float*)d_in[3];
    const int*   batch = (const int*)d_in[4];
    const float* W1a   = (const float*)d_in[5];
    const float* b1a   = (const float*)d_in[6];
    const float* W1b   = (const float*)d_in[7];
    const float* b1b   = (const float*)d_in[8];
    const float* W2a   = (const float*)d_in[9];
    const float* b2a   = (const float*)d_in[10];
    const float* W2b   = (const float*)d_in[11];
    const float* b2b   = (const float*)d_in[12];
    float* out = (float*)d_out;

    const int N = in_sizes[0] / 32;
    const int E = in_sizes[1] / 2;
    const int* erow = eidx;
    const int* ecol = eidx + E;

    float* summed = (float*)d_ws;                 // [N,64]
    float* counts = summed + (size_t)N * 64;      // [N]
    hipMemsetAsync(d_ws, 0, ((size_t)N * 64 + N) * sizeof(float), stream);

    count_rows<<<2048, 256, 0, stream>>>(erow, counts, E);
    edge_mlp_mfma<<<4096, 256, 0, stream>>>(x, erow, ecol, eattr,
                                            W1a, b1a, W1b, b1b, summed, E);
    node_mlp<<<1024, 256, 0, stream>>>(x, summed, counts, u, batch,
                                       W2a, b2a, W2b, b2b, out, N);
}

// Round 5
// 375.919 us; speedup vs baseline: 4.1165x; 1.3606x over previous
//
#include <hip/hip_runtime.h>
#include <hip/hip_bf16.h>

// NodeModel: edge MLP ([x[col]||edge_attr] -> 64 relu -> 64 relu) -> scatter_mean
// over row -> node MLP ([x||agg||u[batch]] -> 64 relu -> 32).
// N=50000, E=1.6M, D_H=64.
//
// R5: R4 (counting-sort by dest row + segment-reduced coalesced scatter +
// MFMA node MLP) with the node staging BUG fixed: each of 4 lanes/node now
// writes its full 32-float segment (4 swizzled bf16x8 chunks) so all 16
// chunks of the 128-wide LDS row are initialized. D2 scratch stride 64->68
// to break a 4-way LDS bank conflict on the edge-major store.

typedef __attribute__((ext_vector_type(8))) short bf16x8;
typedef __attribute__((ext_vector_type(4))) float f32x4;

__device__ __forceinline__ unsigned short f2bf(float f) {
    union { float f; unsigned u; } v; v.f = f;
    return (unsigned short)((v.u + 0x7FFFu + ((v.u >> 16) & 1u)) >> 16);
}

// ---------------- counting sort ----------------

__global__ __launch_bounds__(256) void count_rows(
    const int* __restrict__ erow, int* __restrict__ counts, int E)
{
    int i = blockIdx.x * blockDim.x + threadIdx.x;
    const int stride = gridDim.x * blockDim.x;
    for (; i < E; i += stride) atomicAdd(&counts[erow[i]], 1);
}

__global__ __launch_bounds__(256) void scan_blocks(
    const int* __restrict__ counts, int* __restrict__ excl,
    int* __restrict__ bsum, int N)
{
    __shared__ int tmp[256];
    const int t = threadIdx.x;
    const int i = blockIdx.x * 256 + t;
    const int v = (i < N) ? counts[i] : 0;
    tmp[t] = v; __syncthreads();
#pragma unroll
    for (int o = 1; o < 256; o <<= 1) {
        const int a = (t >= o) ? tmp[t - o] : 0;
        __syncthreads();
        tmp[t] += a;
        __syncthreads();
    }
    if (i < N) excl[i] = tmp[t] - v;
    if (t == 255) bsum[blockIdx.x] = tmp[t];
}

__global__ __launch_bounds__(256) void scan_bsum(int* __restrict__ bsum, int nb)
{
    __shared__ int tmp[256];
    const int t = threadIdx.x;
    const int v = (t < nb) ? bsum[t] : 0;
    tmp[t] = v; __syncthreads();
#pragma unroll
    for (int o = 1; o < 256; o <<= 1) {
        const int a = (t >= o) ? tmp[t - o] : 0;
        __syncthreads();
        tmp[t] += a;
        __syncthreads();
    }
    if (t < nb) bsum[t] = tmp[t] - v;   // exclusive
}

__global__ __launch_bounds__(256) void scan_add(
    int* __restrict__ rowstart, const int* __restrict__ bsum, int N, int E)
{
    const int i = blockIdx.x * 256 + threadIdx.x;
    if (i < N) rowstart[i] += bsum[blockIdx.x];
    if (i == 0) rowstart[N] = E;
}

// sorted4[pos] = {edge_id, col, row, 0}
__global__ __launch_bounds__(256) void permute_edges(
    const int* __restrict__ erow, const int* __restrict__ ecol,
    int* __restrict__ cursor, int4* __restrict__ sorted4, int E)
{
    int i = blockIdx.x * blockDim.x + threadIdx.x;
    const int stride = gridDim.x * blockDim.x;
    for (; i < E; i += stride) {
        const int r = erow[i];
        const int c = ecol[i];
        const int pos = atomicAdd(&cursor[r], 1);
        sorted4[pos] = int4{i, c, r, 0};
    }
}

// ---------------- edge MLP (sorted) + segment-reduced scatter ----------------

#define D2S 68   // D2 row stride (floats); 68 breaks the 4-way store conflict

__global__ __launch_bounds__(256, 3) void edge_mlp_mfma(
    const float* __restrict__ x,        // [N,32]
    const int4*  __restrict__ sorted4,  // [E] {eid,col,row,0}
    const float* __restrict__ eattr,    // [E,32]
    const float* __restrict__ W1a,      // [64,64] (in,out)
    const float* __restrict__ b1a,      // [64]
    const float* __restrict__ W1b,      // [64,64]
    const float* __restrict__ b1b,      // [64]
    float* __restrict__ summed,         // [N,64]
    int E)
{
    __shared__ __align__(16) unsigned short In[64 * 64];   // 8KB
    __shared__ __align__(16) unsigned short H2[64 * 64];   // 8KB
    __shared__ __align__(16) float          D2[64 * D2S];  // 17KB

    const int tid  = threadIdx.x;
    const int lane = tid & 63;
    const int wv   = tid >> 6;
    const int g    = lane >> 4;
    const int el   = lane & 15;

    // persistent weight fragments: A row = lane&15, k = 8*(lane>>4)+j;
    // B col = lane&15, same k (identical mappings)
    bf16x8 wa[4][2], wb[4][2];
    f32x4  bias1[4];
    float  bias2s[4];
#pragma unroll
    for (int mt = 0; mt < 4; ++mt) {
        const int o = mt * 16 + el;
#pragma unroll
        for (int ks = 0; ks < 2; ++ks) {
            bf16x8 ta, tb;
#pragma unroll
            for (int j = 0; j < 8; ++j) {
                const int k = ks * 32 + 8 * g + j;
                ta[j] = (short)f2bf(W1a[k * 64 + o]);
                tb[j] = (short)f2bf(W1b[k * 64 + o]);
            }
            wa[mt][ks] = ta;
            wb[mt][ks] = tb;
        }
#pragma unroll
        for (int r = 0; r < 4; ++r) bias1[mt][r] = b1a[mt * 16 + 4 * g + r];
        bias2s[mt] = b1b[o];
    }

    unsigned short* const inrow = In + (wv * 16) * 64;
    unsigned short* const h2row = H2 + (wv * 16) * 64;
    float*          const d2row = D2 + (wv * 16) * D2S;

    const int ntile = (E + 15) >> 4;
    const int wid   = blockIdx.x * 4 + wv;
    const int nw    = gridDim.x * 4;

    for (int t = wid; t < ntile; t += nw) {
        const int ebase = t << 4;

        // ---- stage 16 sorted edges: 4 lanes/edge -> bf16 -> swizzled LDS ----
        {
            const int le  = lane >> 2;
            const int p   = lane & 3;
            const int pos = ebase + le;
            float4 v[4];
            if (pos < E) {
                const int4 s4 = sorted4[pos];
                const float* src;
                if (p < 2) src = x + (size_t)s4.y * 32 + p * 16;
                else       src = eattr + (size_t)s4.x * 32 + (p - 2) * 16;
#pragma unroll
                for (int q = 0; q < 4; ++q) v[q] = ((const float4*)src)[q];
            } else {
#pragma unroll
                for (int q = 0; q < 4; ++q) v[q] = float4{0.f, 0.f, 0.f, 0.f};
            }
            bf16x8 c0, c1;
#pragma unroll
            for (int q = 0; q < 2; ++q) {
                c0[4*q+0] = (short)f2bf(v[q].x);   c0[4*q+1] = (short)f2bf(v[q].y);
                c0[4*q+2] = (short)f2bf(v[q].z);   c0[4*q+3] = (short)f2bf(v[q].w);
                c1[4*q+0] = (short)f2bf(v[q+2].x); c1[4*q+1] = (short)f2bf(v[q+2].y);
                c1[4*q+2] = (short)f2bf(v[q+2].z); c1[4*q+3] = (short)f2bf(v[q+2].w);
            }
            const int sw = le & 7;
            unsigned short* row = inrow + le * 64;
            *(bf16x8*)(row + (((2 * p)     ^ sw) * 8)) = c0;
            *(bf16x8*)(row + (((2 * p + 1) ^ sw) * 8)) = c1;
        }
        // wave-private LDS rows: compiler lgkmcnt orders write->read, no barrier

        const int sw = el & 7;

        // ---- layer 1: D1 = W1a^T (A) x In^T (B) -> neuron-major ----
        const unsigned short* brow = inrow + el * 64;
        const bf16x8 bf0 = *(const bf16x8*)(brow + (((0 + g) ^ sw) * 8));
        const bf16x8 bf1 = *(const bf16x8*)(brow + (((4 + g) ^ sw) * 8));
        f32x4 a0 = bias1[0], a1 = bias1[1], a2 = bias1[2], a3 = bias1[3];
        a0 = __builtin_amdgcn_mfma_f32_16x16x32_bf16(wa[0][0], bf0, a0, 0, 0, 0);
        a1 = __builtin_amdgcn_mfma_f32_16x16x32_bf16(wa[1][0], bf0, a1, 0, 0, 0);
        a2 = __builtin_amdgcn_mfma_f32_16x16x32_bf16(wa[2][0], bf0, a2, 0, 0, 0);
        a3 = __builtin_amdgcn_mfma_f32_16x16x32_bf16(wa[3][0], bf0, a3, 0, 0, 0);
        a0 = __builtin_amdgcn_mfma_f32_16x16x32_bf16(wa[0][1], bf1, a0, 0, 0, 0);
        a1 = __builtin_amdgcn_mfma_f32_16x16x32_bf16(wa[1][1], bf1, a1, 0, 0, 0);
        a2 = __builtin_amdgcn_mfma_f32_16x16x32_bf16(wa[2][1], bf1, a2, 0, 0, 0);
        a3 = __builtin_amdgcn_mfma_f32_16x16x32_bf16(wa[3][1], bf1, a3, 0, 0, 0);

        // ---- relu -> bf16 -> H2 (wave-private, swizzled) ----
        unsigned short* hrow = h2row + el * 64;
        {
            f32x4 accs[4] = {a0, a1, a2, a3};
#pragma unroll
            for (int mt = 0; mt < 4; ++mt) {
                unsigned short pk[4];
#pragma unroll
                for (int r = 0; r < 4; ++r) pk[r] = f2bf(fmaxf(accs[mt][r], 0.f));
                const int hid   = mt * 16 + 4 * g;
                const int chunk = hid >> 3;
                const int off   = hid & 7;
                *(uint2*)(hrow + ((chunk ^ sw) * 8 + off)) = *(uint2*)pk;
            }
        }

        // ---- layer 2, operand-swapped: D2 = H1 (A) x W1b (B) -> EDGE-major ----
        const bf16x8 hb0 = *(const bf16x8*)(hrow + (((0 + g) ^ sw) * 8));
        const bf16x8 hb1 = *(const bf16x8*)(hrow + (((4 + g) ^ sw) * 8));
        f32x4 d0 = {bias2s[0], bias2s[0], bias2s[0], bias2s[0]};
        f32x4 d1 = {bias2s[1], bias2s[1], bias2s[1], bias2s[1]};
        f32x4 d2 = {bias2s[2], bias2s[2], bias2s[2], bias2s[2]};
        f32x4 d3 = {bias2s[3], bias2s[3], bias2s[3], bias2s[3]};
        d0 = __builtin_amdgcn_mfma_f32_16x16x32_bf16(hb0, wb[0][0], d0, 0, 0, 0);
        d1 = __builtin_amdgcn_mfma_f32_16x16x32_bf16(hb0, wb[1][0], d1, 0, 0, 0);
        d2 = __builtin_amdgcn_mfma_f32_16x16x32_bf16(hb0, wb[2][0], d2, 0, 0, 0);
        d3 = __builtin_amdgcn_mfma_f32_16x16x32_bf16(hb0, wb[3][0], d3, 0, 0, 0);
        d0 = __builtin_amdgcn_mfma_f32_16x16x32_bf16(hb1, wb[0][1], d0, 0, 0, 0);
        d1 = __builtin_amdgcn_mfma_f32_16x16x32_bf16(hb1, wb[1][1], d1, 0, 0, 0);
        d2 = __builtin_amdgcn_mfma_f32_16x16x32_bf16(hb1, wb[2][1], d2, 0, 0, 0);
        d3 = __builtin_amdgcn_mfma_f32_16x16x32_bf16(hb1, wb[3][1], d3, 0, 0, 0);

        // ---- relu -> LDS [16 edges][64 neurons] f32 (stride D2S) ----
        {
            f32x4 dd[4] = {d0, d1, d2, d3};
#pragma unroll
            for (int nt = 0; nt < 4; ++nt)
#pragma unroll
                for (int r = 0; r < 4; ++r) {
                    const int eg = ebase + 4 * g + r;
                    d2row[(4 * g + r) * D2S + nt * 16 + el] =
                        (eg < E) ? fmaxf(dd[nt][r], 0.f) : 0.f;
                }
        }

        // ---- segment flush: rows are sorted runs; lane = neuron ----
        const int myrow = (ebase + el < E) ? sorted4[ebase + el].z : -1;
        float acc = 0.f;
        int prev = __shfl(myrow, 0);
#pragma unroll
        for (int j = 0; j < 16; ++j) {
            const float v = d2row[j * D2S + lane];
            const int rj = __shfl(myrow, j);
            if (rj != prev) {                        // wave-uniform branch
                if (prev >= 0)
                    unsafeAtomicAdd(&summed[(size_t)prev * 64 + lane], acc);
                acc = 0.f;
                prev = rj;
            }
            acc += v;
        }
        if (prev >= 0)
            unsafeAtomicAdd(&summed[(size_t)prev * 64 + lane], acc);
    }
}

// ---------------- node MLP via MFMA ----------------

__global__ __launch_bounds__(256, 2) void node_mlp_mfma(
    const float* __restrict__ x,        // [N,32]
    const float* __restrict__ summed,   // [N,64]
    const int*   __restrict__ rowstart, // [N+1]
    const float* __restrict__ u,        // [G,16]
    const int*   __restrict__ batch,    // [N]
    const float* __restrict__ W2a,      // [112,64]
    const float* __restrict__ b2a,      // [64]
    const float* __restrict__ W2b,      // [64,32]
    const float* __restrict__ b2b,      // [32]
    float* __restrict__ out,            // [N,32]
    int N)
{
    __shared__ __align__(16) unsigned short In[64 * 128];  // 16KB
    __shared__ __align__(16) unsigned short H[64 * 64];    // 8KB

    const int tid  = threadIdx.x;
    const int lane = tid & 63;
    const int wv   = tid >> 6;
    const int g    = lane >> 4;
    const int el   = lane & 15;

    // layer-1 A fragments: W2a^T, K padded 112->128
    bf16x8 wa[4][4];
    f32x4  bias1[4];
#pragma unroll
    for (int mt = 0; mt < 4; ++mt) {
        const int o = mt * 16 + el;
#pragma unroll
        for (int ks = 0; ks < 4; ++ks) {
            bf16x8 ta;
#pragma unroll
            for (int j = 0; j < 8; ++j) {
                const int k = ks * 32 + 8 * g + j;
                ta[j] = (k < 112) ? (short)f2bf(W2a[k * 64 + o]) : (short)0;
            }
            wa[mt][ks] = ta;
        }
#pragma unroll
        for (int r = 0; r < 4; ++r) bias1[mt][r] = b2a[mt * 16 + 4 * g + r];
    }
    // layer-2 B fragments: W2b [64,32], out tiles nt=0,1
    bf16x8 wb[2][2];
    float  bias2s[2];
#pragma unroll
    for (int nt = 0; nt < 2; ++nt) {
        const int o = nt * 16 + el;
#pragma unroll
        for (int ks = 0; ks < 2; ++ks) {
            bf16x8 tb;
#pragma unroll
            for (int j = 0; j < 8; ++j) {
                const int k = ks * 32 + 8 * g + j;
                tb[j] = (short)f2bf(W2b[k * 32 + o]);
            }
            wb[nt][ks] = tb;
        }
        bias2s[nt] = b2b[o];
    }

    unsigned short* const inrow = In + (wv * 16) * 128;
    unsigned short* const hrow0 = H + (wv * 16) * 64;

    const int ntile = (N + 15) >> 4;
    const int wid   = blockIdx.x * 4 + wv;
    const int nw    = gridDim.x * 4;

    for (int t = wid; t < ntile; t += nw) {
        const int nbase = t << 4;

        // ---- stage 16 nodes: 4 lanes/node, 32-float segment each ----
        // row layout (128 bf16): [x(32) | agg(32) | agg(32) | u(16)+0(16)]
        {
            const int le = lane >> 2;            // local node 0..15
            const int p  = lane & 3;             // segment
            const int n  = nbase + le;
            float4 v[8];
            if (n < N) {
                if (p == 0) {
                    const float4* xp = (const float4*)(x + (size_t)n * 32);
#pragma unroll
                    for (int q = 0; q < 8; ++q) v[q] = xp[q];
                } else if (p < 3) {
                    const int cnt = rowstart[n + 1] - rowstart[n];
                    const float inv = 1.0f / fmaxf((float)cnt, 1.0f);
                    const float4* sp = (const float4*)(summed + (size_t)n * 64 + (p - 1) * 32);
#pragma unroll
                    for (int q = 0; q < 8; ++q) {
                        v[q] = sp[q];
                        v[q].x *= inv; v[q].y *= inv; v[q].z *= inv; v[q].w *= inv;
                    }
                } else {
                    const int gb = batch[n];
                    const float4* up = (const float4*)(u + (size_t)gb * 16);
#pragma unroll
                    for (int q = 0; q < 4; ++q) v[q] = up[q];
#pragma unroll
                    for (int q = 4; q < 8; ++q) v[q] = float4{0.f, 0.f, 0.f, 0.f};
                }
            } else {
#pragma unroll
                for (int q = 0; q < 8; ++q) v[q] = float4{0.f, 0.f, 0.f, 0.f};
            }
            const int sw = le & 7;
            unsigned short* row = inrow + le * 128;
#pragma unroll
            for (int q = 0; q < 4; ++q) {
                bf16x8 c;
                const float4 va = v[2 * q], vb = v[2 * q + 1];
                c[0] = (short)f2bf(va.x); c[1] = (short)f2bf(va.y);
                c[2] = (short)f2bf(va.z); c[3] = (short)f2bf(va.w);
                c[4] = (short)f2bf(vb.x); c[5] = (short)f2bf(vb.y);
                c[6] = (short)f2bf(vb.z); c[7] = (short)f2bf(vb.w);
                const int cc = 4 * p + q;                    // chunk id 0..15
                const int ci = (cc & 8) | ((cc & 7) ^ sw);   // swizzled
                *(bf16x8*)(row + ci * 8) = c;
            }
        }
        // wave-private rows, no barrier needed

        // ---- layer 1: 16 MFMAs over K=128 ----
        const unsigned short* brow = inrow + el * 128;
        const int sw7 = el & 7;
        f32x4 a0 = bias1[0], a1 = bias1[1], a2 = bias1[2], a3 = bias1[3];
#pragma unroll
        for (int ks = 0; ks < 4; ++ks) {
            const int cc = ks * 4 + g;          // chunk carrying k=ks*32+8g..+7
            const int ci = (cc & 8) | ((cc & 7) ^ sw7);
            const bf16x8 bf = *(const bf16x8*)(brow + ci * 8);
            a0 = __builtin_amdgcn_mfma_f32_16x16x32_bf16(wa[0][ks], bf, a0, 0, 0, 0);
            a1 = __builtin_amdgcn_mfma_f32_16x16x32_bf16(wa[1][ks], bf, a1, 0, 0, 0);
            a2 = __builtin_amdgcn_mfma_f32_16x16x32_bf16(wa[2][ks], bf, a2, 0, 0, 0);
            a3 = __builtin_amdgcn_mfma_f32_16x16x32_bf16(wa[3][ks], bf, a3, 0, 0, 0);
        }

        // ---- relu -> bf16 -> H (swizzled by el&7) ----
        unsigned short* hrow = hrow0 + el * 64;
        {
            f32x4 accs[4] = {a0, a1, a2, a3};
#pragma unroll
            for (int mt = 0; mt < 4; ++mt) {
                unsigned short pk[4];
#pragma unroll
                for (int r = 0; r < 4; ++r) pk[r] = f2bf(fmaxf(accs[mt][r], 0.f));
                const int hid   = mt * 16 + 4 * g;
                const int chunk = hid >> 3;
                const int off   = hid & 7;
                *(uint2*)(hrow + ((chunk ^ sw7) * 8 + off)) = *(uint2*)pk;
            }
        }

        // ---- layer 2 operand-swapped: D = H (A) x W2b (B) -> node-major ----
        const bf16x8 hb0 = *(const bf16x8*)(hrow + (((0 + g) ^ sw7) * 8));
        const bf16x8 hb1 = *(const bf16x8*)(hrow + (((4 + g) ^ sw7) * 8));
        f32x4 dn0 = {bias2s[0], bias2s[0], bias2s[0], bias2s[0]};
        f32x4 dn1 = {bias2s[1], bias2s[1], bias2s[1], bias2s[1]};
        dn0 = __builtin_amdgcn_mfma_f32_16x16x32_bf16(hb0, wb[0][0], dn0, 0, 0, 0);
        dn1 = __builtin_amdgcn_mfma_f32_16x16x32_bf16(hb0, wb[1][0], dn1, 0, 0, 0);
        dn0 = __builtin_amdgcn_mfma_f32_16x16x32_bf16(hb1, wb[0][1], dn0, 0, 0, 0);
        dn1 = __builtin_amdgcn_mfma_f32_16x16x32_bf16(hb1, wb[1][1], dn1, 0, 0, 0);

        // ---- store: lane holds node 4g+r, out nt*16+el ----
        if (nbase + 16 <= N) {
#pragma unroll
            for (int r = 0; r < 4; ++r) {
                float* dst = out + (size_t)(nbase + 4 * g + r) * 32 + el;
                dst[0]  = dn0[r];
                dst[16] = dn1[r];
            }
        } else {
#pragma unroll
            for (int r = 0; r < 4; ++r) {
                const int n = nbase + 4 * g + r;
                if (n < N) {
                    float* dst = out + (size_t)n * 32 + el;
                    dst[0]  = dn0[r];
                    dst[16] = dn1[r];
                }
            }
        }
    }
}

extern "C" void kernel_launch(void* const* d_in, const int* in_sizes, int n_in,
                              void* d_out, int out_size, void* d_ws, size_t ws_size,
                              hipStream_t stream) {
    const float* x     = (const float*)d_in[0];
    const int*   eidx  = (const int*)d_in[1];   // [2,E] int32
    const float* eattr = (const float*)d_in[2];
    const float* u     = (const float*)d_in[3];
    const int*   batch = (const int*)d_in[4];
    const float* W1a   = (const float*)d_in[5];
    const float* b1a   = (const float*)d_in[6];
    const float* W1b   = (const float*)d_in[7];
    const float* b1b   = (const float*)d_in[8];
    const float* W2a   = (const float*)d_in[9];
    const float* b2a   = (const float*)d_in[10];
    const float* W2b   = (const float*)d_in[11];
    const float* b2b   = (const float*)d_in[12];
    float* out = (float*)d_out;

    const int N = in_sizes[0] / 32;
    const int E = in_sizes[1] / 2;
    const int* erow = eidx;
    const int* ecol = eidx + E;

    // ws: sorted4[E] | summed[N*64] f32 | counts[N] | rowstart[N+1] | cursor[N] | bsum[256]
    int4*  sorted4  = (int4*)d_ws;
    float* summed   = (float*)(sorted4 + E);
    int*   counts   = (int*)(summed + (size_t)N * 64);
    int*   rowstart = counts + N;
    int*   cursor   = rowstart + (N + 1);
    int*   bsum     = cursor + N;

    // zero summed + counts (contiguous)
    hipMemsetAsync(summed, 0, ((size_t)N * 64 + N) * sizeof(float), stream);

    count_rows<<<2048, 256, 0, stream>>>(erow, counts, E);
    const int nb = (N + 255) / 256;
    scan_blocks<<<nb, 256, 0, stream>>>(counts, rowstart, bsum, N);
    scan_bsum<<<1, 256, 0, stream>>>(bsum, nb);
    scan_add<<<nb, 256, 0, stream>>>(rowstart, bsum, N, E);
    hipMemcpyAsync(cursor, rowstart, (size_t)N * sizeof(int),
                   hipMemcpyDeviceToDevice, stream);
    permute_edges<<<2048, 256, 0, stream>>>(erow, ecol, cursor, sorted4, E);

    edge_mlp_mfma<<<4096, 256, 0, stream>>>(x, sorted4, eattr,
                                            W1a, b1a, W1b, b1b, summed, E);
    node_mlp_mfma<<<784, 256, 0, stream>>>(x, summed, rowstart, u, batch,
                                           W2a, b2a, W2b, b2b, out, N);
}